// Round 11
// baseline (886.362 us; speedup 1.0000x reference)
//
#include <hip/hip_runtime.h>

#define Hdim 256
static const int E_N  = 260640;
static const int NG_N = 65160;
static const int NM_N = 40962;

typedef __attribute__((ext_vector_type(8))) __bf16 bf16x8;
typedef __attribute__((ext_vector_type(8))) unsigned short u16x8;
typedef __attribute__((ext_vector_type(4))) float f32x4;

__device__ __forceinline__ unsigned short f2bf(float f) {
  unsigned u = __float_as_uint(f);
  u = (u + 0x7FFFu + ((u >> 16) & 1u)) >> 16;
  return (unsigned short)u;
}
__device__ __forceinline__ float bf2f(unsigned short h) {
  return __uint_as_float((unsigned)h << 16);
}
struct BfPair { unsigned short hi, lo; };
// RNE split (weights pre-pass)
__device__ __forceinline__ BfPair split2(float f) {
  BfPair r;
  r.hi = f2bf(f);
  r.lo = f2bf(f - bf2f(r.hi));
  return r;
}
// truncation split (activations in 3-product mode; lo compensates trunc error)
__device__ __forceinline__ BfPair split2t(float f) {
  unsigned u = __float_as_uint(f);
  BfPair r;
  r.hi = (unsigned short)(u >> 16);
  r.lo = f2bf(f - __uint_as_float(u & 0xffff0000u));
  return r;
}
// LDS-visibility barrier that does NOT drain vmcnt (keeps prefetch in flight)
__device__ __forceinline__ void bar_lds() {
  asm volatile("s_waitcnt lgkmcnt(0)" ::: "memory");
  __builtin_amdgcn_s_barrier();
}

// W [K][N] f32 -> WT_hi/WT_lo [N][K] bf16 split (one-shot pre-pass)
__global__ void wtrans_kernel(const float* __restrict__ W,
                              unsigned short* __restrict__ WThi,
                              unsigned short* __restrict__ WTlo, int K, int N) {
  int i = blockIdx.x * 256 + threadIdx.x;
  if (i >= K * N) return;
  int n = i / K;
  int k = i - n * K;
  BfPair p = split2(W[(long)k * N + n]);
  WThi[i] = p.hi;
  WTlo[i] = p.lo;
}

// A rows padded to 72 elems (144B); h rows padded to 264 (528B).
template <bool A3>
struct SMem {
  unsigned short ahi[2][64][72];           // A hi dbuf                 18 KB
  unsigned short alo[A3 ? 2 : 1][A3 ? 64 : 1][A3 ? 72 : 1];  // lo (3-prod only)
  unsigned short hh[64 * 264];             // h (bf16 hi)               33 KB
  float lnp[4][64][2];                     // LN partials                2 KB
};

// out = LN(silu(cat(segs)@W1+b1)@W2+b2)*g+b  [+residual store | atomic scatter]
// layer1: A3 ? 3-product : 2-product (A-hi RNE); layer2: 2-product.
template <int NSEG, bool SCATTER, bool A3>
__launch_bounds__(256, 2)
__global__ void mlp_mfma(
    const float* s0, const float* s1, const float* s2,
    const int* __restrict__ i1, const int* __restrict__ i2, int M,
    const unsigned short* __restrict__ W1Th, const unsigned short* __restrict__ W1Tl,
    const float* __restrict__ b1,
    const unsigned short* __restrict__ W2Th, const unsigned short* __restrict__ W2Tl,
    const float* __restrict__ b2,
    const float* __restrict__ gamma, const float* __restrict__ beta,
    const float* residual, float* outp,
    float* agg, const int* __restrict__ scat) {
  constexpr int K1 = NSEG * 256;
  constexpr int NT = K1 / 32;   // 32-k MFMA steps
  constexpr int NU = K1 / 64;   // 64-k macro steps (1 barrier each)
  __shared__ SMem<A3> sm;

  const int tid = threadIdx.x;
  const int w = tid >> 6;        // wave: owns output cols [w*64, w*64+64)
  const int l = tid & 63;
  const int lr = l & 15;
  const int lg = l >> 4;
  const int colbase = w * 64 + lr;
  const long blockRow = (long)blockIdx.x * 64;

  // staging: thread (w,l) stages row l, k-cols [w*16, w*16+16) of each macro tile
  const long grow_s = blockRow + l;
  const long growc = grow_s < M ? grow_s : (long)(M - 1);
  const float* rp0 = s0 + growc * Hdim;
  const float* rp1 = nullptr;
  const float* rp2 = nullptr;
  if (NSEG >= 2) rp1 = s1 + (long)(i1 ? i1[growc] : (int)growc) * Hdim;
  if (NSEG >= 3) rp2 = s2 + (long)(i2 ? i2[growc] : (int)growc) * Hdim;

  auto aptr = [&](int m) -> const float* {   // macro m covers k [m*64, m*64+64)
    const int seg = m >> 2;
    const float* rp = rp0;
    if (NSEG >= 2 && seg == 1) rp = rp1;
    if (NSEG >= 3 && seg == 2) rp = rp2;
    return rp + (m & 3) * 64 + w * 16;
  };

  auto loadA = [&](int m, float4* v) {
    const float* p = aptr(m);
#pragma unroll
    for (int i = 0; i < 4; ++i) v[i] = *(const float4*)(p + i * 4);
  };

  auto stageA = [&](int buf, const float4* v) {
    float in[16] = {v[0].x, v[0].y, v[0].z, v[0].w, v[1].x, v[1].y, v[1].z, v[1].w,
                    v[2].x, v[2].y, v[2].z, v[2].w, v[3].x, v[3].y, v[3].z, v[3].w};
    if constexpr (A3) {
      u16x8 th0, tl0, th1, tl1;
#pragma unroll
      for (int j = 0; j < 8; ++j) {
        BfPair p0 = split2t(in[j]);
        th0[j] = p0.hi; tl0[j] = p0.lo;
        BfPair p1 = split2t(in[j + 8]);
        th1[j] = p1.hi; tl1[j] = p1.lo;
      }
      *(u16x8*)&sm.ahi[buf][l][w * 16]     = th0;
      *(u16x8*)&sm.ahi[buf][l][w * 16 + 8] = th1;
      *(u16x8*)&sm.alo[buf][l][w * 16]     = tl0;
      *(u16x8*)&sm.alo[buf][l][w * 16 + 8] = tl1;
    } else {
      u16x8 th0, th1;
#pragma unroll
      for (int j = 0; j < 8; ++j) {
        th0[j] = f2bf(in[j]);       // RNE: unbiased without lo-compensation
        th1[j] = f2bf(in[j + 8]);
      }
      *(u16x8*)&sm.ahi[buf][l][w * 16]     = th0;
      *(u16x8*)&sm.ahi[buf][l][w * 16 + 8] = th1;
    }
  };

  auto loadB1 = [&](int t, bf16x8* bh, bf16x8* bl) {   // 32-k step t
#pragma unroll
    for (int n = 0; n < 4; ++n) {
      const long off = (long)(colbase + n * 16) * K1 + t * 32 + lg * 8;
      bh[n] = *(const bf16x8*)(W1Th + off);
      bl[n] = *(const bf16x8*)(W1Tl + off);
    }
  };

  // ---------------- layer 1: cat(segs) @ W1 (macro-pipelined, A depth-3) ----------------
  f32x4 acc[4][4] = {};
  {
    float4 v[4];
    loadA(0, v);
    stageA(0, v);
  }
  // rotation: va = A(u+1), vb = A(u+2), vc = A(u+3) in flight
  float4 va[4], vb[4], vc[4];
  loadA(1 < NU ? 1 : NU - 1, va);
  loadA(2 < NU ? 2 : NU - 1, vb);
  bf16x8 bhc[4], blc[4];
  loadB1(0, bhc, blc);

  for (int u = 0; u < NU; ++u) {
    bar_lds();                       // buf[u&1] visible; no vmcnt drain
    // issue A(u+3) loads now -> ~2.7 macros of latency cover
    loadA(u + 3 < NU ? u + 3 : NU - 1, vc);
    // ---- k-step s=0 (t = 2u) ----
    bf16x8 bhn[4], bln[4];
    loadB1(2 * u + 1 < NT ? 2 * u + 1 : NT - 1, bhn, bln);
    bf16x8 ah[4], al[4];
#pragma unroll
    for (int rb = 0; rb < 4; ++rb) {
      ah[rb] = *(const bf16x8*)&sm.ahi[u & 1][rb * 16 + lr][lg * 8];
      if constexpr (A3) al[rb] = *(const bf16x8*)&sm.alo[u & 1][rb * 16 + lr][lg * 8];
    }
    __builtin_amdgcn_s_setprio(1);
#pragma unroll
    for (int rb = 0; rb < 4; ++rb)
#pragma unroll
      for (int n = 0; n < 4; ++n) {
        acc[rb][n] = __builtin_amdgcn_mfma_f32_16x16x32_bf16(ah[rb], bhc[n], acc[rb][n], 0, 0, 0);
        acc[rb][n] = __builtin_amdgcn_mfma_f32_16x16x32_bf16(ah[rb], blc[n], acc[rb][n], 0, 0, 0);
        if constexpr (A3)
          acc[rb][n] = __builtin_amdgcn_mfma_f32_16x16x32_bf16(al[rb], bhc[n], acc[rb][n], 0, 0, 0);
      }
    __builtin_amdgcn_s_setprio(0);
    // ---- k-step s=1 (t = 2u+1) ----
    bf16x8 bh2[4], bl2[4];
    loadB1(2 * u + 2 < NT ? 2 * u + 2 : NT - 1, bh2, bl2);
#pragma unroll
    for (int rb = 0; rb < 4; ++rb) {
      ah[rb] = *(const bf16x8*)&sm.ahi[u & 1][rb * 16 + lr][32 + lg * 8];
      if constexpr (A3) al[rb] = *(const bf16x8*)&sm.alo[u & 1][rb * 16 + lr][32 + lg * 8];
    }
    __builtin_amdgcn_s_setprio(1);
#pragma unroll
    for (int rb = 0; rb < 4; ++rb)
#pragma unroll
      for (int n = 0; n < 4; ++n) {
        acc[rb][n] = __builtin_amdgcn_mfma_f32_16x16x32_bf16(ah[rb], bhn[n], acc[rb][n], 0, 0, 0);
        acc[rb][n] = __builtin_amdgcn_mfma_f32_16x16x32_bf16(ah[rb], bln[n], acc[rb][n], 0, 0, 0);
        if constexpr (A3)
          acc[rb][n] = __builtin_amdgcn_mfma_f32_16x16x32_bf16(al[rb], bhn[n], acc[rb][n], 0, 0, 0);
      }
    __builtin_amdgcn_s_setprio(0);
    // ---- stage A(u+1) (loads have been in flight ~3 macros) ----
    if (u + 1 < NU) stageA((u + 1) & 1, va);
    // rotate prefetch buffers
#pragma unroll
    for (int i = 0; i < 4; ++i) { va[i] = vb[i]; vb[i] = vc[i]; }
#pragma unroll
    for (int n = 0; n < 4; ++n) { bhc[n] = bh2[n]; blc[n] = bl2[n]; }
  }

  // issue B2(0) prefetch early (hides under SiLU + h-store)
  bf16x8 b2hc[4], b2lc[4];
#pragma unroll
  for (int n = 0; n < 4; ++n) {
    const long off = (long)(colbase + n * 16) * 256 + lg * 8;
    b2hc[n] = *(const bf16x8*)(W2Th + off);
    b2lc[n] = *(const bf16x8*)(W2Tl + off);
  }

  // ---------------- bias1 + SiLU -> h (bf16 hi, padded rows) ----------------
  float bb1[4];
#pragma unroll
  for (int n = 0; n < 4; ++n) bb1[n] = b1[colbase + n * 16];
#pragma unroll
  for (int rb = 0; rb < 4; ++rb) {
#pragma unroll
    for (int n = 0; n < 4; ++n) {
      const int col = colbase + n * 16;
#pragma unroll
      for (int r = 0; r < 4; ++r) {
        const int row = rb * 16 + lg * 4 + r;
        float v = acc[rb][n][r] + bb1[n];
        v = v / (1.0f + __expf(-v));
        sm.hh[row * 264 + col] = f2bf(v);
      }
    }
  }
  bar_lds();

  // ---------------- layer 2: h @ W2 (2-product, no barriers) ----------------
  f32x4 acc2[4][4] = {};
  for (int ks = 0; ks < 8; ++ks) {
    const int kn = (ks + 1 < 8) ? ks + 1 : ks;
    bf16x8 b2hn[4], b2ln[4];
#pragma unroll
    for (int n = 0; n < 4; ++n) {
      const long off = (long)(colbase + n * 16) * 256 + kn * 32 + lg * 8;
      b2hn[n] = *(const bf16x8*)(W2Th + off);
      b2ln[n] = *(const bf16x8*)(W2Tl + off);
    }
    bf16x8 ah[4];
#pragma unroll
    for (int rb = 0; rb < 4; ++rb) {
      const int row = rb * 16 + lr;
      ah[rb] = *(const bf16x8*)&sm.hh[row * 264 + ks * 32 + lg * 8];
    }
    __builtin_amdgcn_s_setprio(1);
#pragma unroll
    for (int rb = 0; rb < 4; ++rb)
#pragma unroll
      for (int n = 0; n < 4; ++n) {
        acc2[rb][n] = __builtin_amdgcn_mfma_f32_16x16x32_bf16(ah[rb], b2hc[n], acc2[rb][n], 0, 0, 0);
        acc2[rb][n] = __builtin_amdgcn_mfma_f32_16x16x32_bf16(ah[rb], b2lc[n], acc2[rb][n], 0, 0, 0);
      }
    __builtin_amdgcn_s_setprio(0);
#pragma unroll
    for (int n = 0; n < 4; ++n) { b2hc[n] = b2hn[n]; b2lc[n] = b2ln[n]; }
  }

  // ---------------- LayerNorm in registers (two-pass) + epilogue ----------------
  float bb2[4], gmv[4], btv[4];
#pragma unroll
  for (int n = 0; n < 4; ++n) {
    const int c = colbase + n * 16;
    bb2[n] = b2[c];
    gmv[n] = gamma[c];
    btv[n] = beta[c];
  }
  float psum[16];
#pragma unroll
  for (int rb = 0; rb < 4; ++rb)
#pragma unroll
    for (int r = 0; r < 4; ++r) {
      float s = 0.f;
#pragma unroll
      for (int n = 0; n < 4; ++n) s += acc2[rb][n][r] + bb2[n];
      psum[rb * 4 + r] = s;
    }
#pragma unroll
  for (int i = 0; i < 16; ++i) {
    psum[i] += __shfl_xor(psum[i], 1, 64);
    psum[i] += __shfl_xor(psum[i], 2, 64);
    psum[i] += __shfl_xor(psum[i], 4, 64);
    psum[i] += __shfl_xor(psum[i], 8, 64);
  }
  if (lr == 0) {
#pragma unroll
    for (int rb = 0; rb < 4; ++rb)
#pragma unroll
      for (int r = 0; r < 4; ++r)
        sm.lnp[w][rb * 16 + lg * 4 + r][0] = psum[rb * 4 + r];
  }
  __syncthreads();
  float mu[16];
#pragma unroll
  for (int rb = 0; rb < 4; ++rb)
#pragma unroll
    for (int r = 0; r < 4; ++r) {
      const int row = rb * 16 + lg * 4 + r;
      mu[rb * 4 + r] = (sm.lnp[0][row][0] + sm.lnp[1][row][0] +
                        sm.lnp[2][row][0] + sm.lnp[3][row][0]) * (1.0f / 256.0f);
    }
  float psq[16];
#pragma unroll
  for (int rb = 0; rb < 4; ++rb)
#pragma unroll
    for (int r = 0; r < 4; ++r) {
      float s = 0.f;
#pragma unroll
      for (int n = 0; n < 4; ++n) {
        const float d = acc2[rb][n][r] + bb2[n] - mu[rb * 4 + r];
        s += d * d;
      }
      psq[rb * 4 + r] = s;
    }
#pragma unroll
  for (int i = 0; i < 16; ++i) {
    psq[i] += __shfl_xor(psq[i], 1, 64);
    psq[i] += __shfl_xor(psq[i], 2, 64);
    psq[i] += __shfl_xor(psq[i], 4, 64);
    psq[i] += __shfl_xor(psq[i], 8, 64);
  }
  if (lr == 0) {
#pragma unroll
    for (int rb = 0; rb < 4; ++rb)
#pragma unroll
      for (int r = 0; r < 4; ++r)
        sm.lnp[w][rb * 16 + lg * 4 + r][1] = psq[rb * 4 + r];
  }
  __syncthreads();
#pragma unroll
  for (int rb = 0; rb < 4; ++rb) {
#pragma unroll
    for (int r = 0; r < 4; ++r) {
      const int row = rb * 16 + lg * 4 + r;
      const long grow = blockRow + row;
      if (grow >= M) continue;
      const float var = (sm.lnp[0][row][1] + sm.lnp[1][row][1] +
                         sm.lnp[2][row][1] + sm.lnp[3][row][1]) * (1.0f / 256.0f);
      const float rstd = 1.0f / sqrtf(var + 1e-5f);
      const float m = mu[rb * 4 + r];
      if constexpr (SCATTER) {
        const int d = scat[grow];
        float* ap = agg + (long)d * Hdim;
#pragma unroll
        for (int n = 0; n < 4; ++n) {
          const int c = colbase + n * 16;
          atomicAdd(ap + c, (acc2[rb][n][r] + bb2[n] - m) * rstd * gmv[n] + btv[n]);
        }
      } else {
        const long o = grow * Hdim;
#pragma unroll
        for (int n = 0; n < 4; ++n) {
          const int c = colbase + n * 16;
          outp[o + c] = (acc2[rb][n][r] + bb2[n] - m) * rstd * gmv[n] + btv[n] + residual[o + c];
        }
      }
    }
  }
}

extern "C" void kernel_launch(void* const* d_in, const int* in_sizes, int n_in,
                              void* d_out, int out_size, void* d_ws, size_t ws_size,
                              hipStream_t stream) {
  const float* g2m   = (const float*)d_in[0];
  const float* gridf = (const float*)d_in[1];
  const float* meshf = (const float*)d_in[2];
  const int*   src   = (const int*)d_in[3];
  const int*   dst   = (const int*)d_in[4];
  const float* eW1 = (const float*)d_in[5];  const float* eb1 = (const float*)d_in[6];
  const float* eW2 = (const float*)d_in[7];  const float* eb2 = (const float*)d_in[8];
  const float* eg  = (const float*)d_in[9];  const float* ebt = (const float*)d_in[10];
  const float* sW1 = (const float*)d_in[11]; const float* sb1 = (const float*)d_in[12];
  const float* sW2 = (const float*)d_in[13]; const float* sb2 = (const float*)d_in[14];
  const float* sg  = (const float*)d_in[15]; const float* sbt = (const float*)d_in[16];
  const float* dW1 = (const float*)d_in[17]; const float* db1 = (const float*)d_in[18];
  const float* dW2 = (const float*)d_in[19]; const float* db2 = (const float*)d_in[20];
  const float* dg  = (const float*)d_in[21]; const float* dbt = (const float*)d_in[22];

  float* out_grid = (float*)d_out;
  float* out_mesh = out_grid + (long)NG_N * Hdim;  // doubles as agg accumulator

  // split-bf16 transposed weights in workspace (~2.4 MB)
  unsigned short* p = (unsigned short*)d_ws;
  unsigned short* eW1Th = p; p += 768 * 256;  unsigned short* eW1Tl = p; p += 768 * 256;
  unsigned short* eW2Th = p; p += 256 * 256;  unsigned short* eW2Tl = p; p += 256 * 256;
  unsigned short* sW1Th = p; p += 256 * 256;  unsigned short* sW1Tl = p; p += 256 * 256;
  unsigned short* sW2Th = p; p += 256 * 256;  unsigned short* sW2Tl = p; p += 256 * 256;
  unsigned short* dW1Th = p; p += 512 * 256;  unsigned short* dW1Tl = p; p += 512 * 256;
  unsigned short* dW2Th = p; p += 256 * 256;  unsigned short* dW2Tl = p; p += 256 * 256;

  auto WT = [&](const float* W, unsigned short* Th, unsigned short* Tl, int K, int N) {
    int tot = K * N;
    wtrans_kernel<<<(tot + 255) / 256, 256, 0, stream>>>(W, Th, Tl, K, N);
  };
  WT(eW1, eW1Th, eW1Tl, 768, 256);
  WT(eW2, eW2Th, eW2Tl, 256, 256);
  WT(sW1, sW1Th, sW1Tl, 256, 256);
  WT(sW2, sW2Th, sW2Tl, 256, 256);
  WT(dW1, dW1Th, dW1Tl, 512, 256);
  WT(dW2, dW2Th, dW2Tl, 256, 256);

  // zero the agg accumulator (mesh output region)
  (void)hipMemsetAsync(out_mesh, 0, (size_t)NM_N * Hdim * sizeof(float), stream);

  // edge MLP (2-product layer1): cat[g2m, grid[src], mesh[dst]] -> scatter into agg
  mlp_mfma<3, true, false><<<(E_N + 63) / 64, 256, 0, stream>>>(
      g2m, gridf, meshf, src, dst, E_N,
      eW1Th, eW1Tl, eb1, eW2Th, eW2Tl, eb2, eg, ebt,
      nullptr, nullptr, out_mesh, dst);

  // grid MLP (3-product): grid_new = grid + MLP(grid)
  mlp_mfma<1, false, true><<<(NG_N + 63) / 64, 256, 0, stream>>>(
      gridf, nullptr, nullptr, nullptr, nullptr, NG_N,
      sW1Th, sW1Tl, sb1, sW2Th, sW2Tl, sb2, sg, sbt,
      gridf, out_grid, nullptr, nullptr);

  // mesh MLP (3-product): mesh_new = mesh + MLP(cat[agg, mesh])
  mlp_mfma<2, false, true><<<(NM_N + 63) / 64, 256, 0, stream>>>(
      out_mesh, meshf, nullptr, nullptr, nullptr, NM_N,
      dW1Th, dW1Tl, db1, dW2Th, dW2Tl, db2, dg, dbt,
      meshf, out_mesh, nullptr, nullptr);
}

// Round 12
// 752.164 us; speedup vs baseline: 1.1784x; 1.1784x over previous
//
#include <hip/hip_runtime.h>

#define Hdim 256
static const int E_N  = 260640;
static const int NG_N = 65160;
static const int NM_N = 40962;

typedef __attribute__((ext_vector_type(8))) __bf16 bf16x8;
typedef __attribute__((ext_vector_type(8))) unsigned short u16x8;
typedef __attribute__((ext_vector_type(4))) float f32x4;

__device__ __forceinline__ unsigned short f2bf(float f) {
  unsigned u = __float_as_uint(f);
  u = (u + 0x7FFFu + ((u >> 16) & 1u)) >> 16;
  return (unsigned short)u;
}
__device__ __forceinline__ float bf2f(unsigned short h) {
  return __uint_as_float((unsigned)h << 16);
}
struct BfPair { unsigned short hi, lo; };
// RNE split (weights pre-pass)
__device__ __forceinline__ BfPair split2(float f) {
  BfPair r;
  r.hi = f2bf(f);
  r.lo = f2bf(f - bf2f(r.hi));
  return r;
}
// truncation split (activations in 3-product mode; lo compensates trunc error)
__device__ __forceinline__ BfPair split2t(float f) {
  unsigned u = __float_as_uint(f);
  BfPair r;
  r.hi = (unsigned short)(u >> 16);
  r.lo = f2bf(f - __uint_as_float(u & 0xffff0000u));
  return r;
}
// LDS-visibility barrier that does NOT drain vmcnt (keeps prefetch in flight)
__device__ __forceinline__ void bar_lds() {
  asm volatile("s_waitcnt lgkmcnt(0)" ::: "memory");
  __builtin_amdgcn_s_barrier();
}

// W [K][N=256] f32 -> fragment-major split-bf16:
// F[((k/32)*16 + col/16)*64 + lane][8]  with lane = ((k%32)/8)*16 + col%16,
// element j = k%8. A wave's B-fragment load is then one contiguous 1KB burst.
__global__ void wfrag_kernel(const float* __restrict__ W,
                             unsigned short* __restrict__ Fh,
                             unsigned short* __restrict__ Fl, int K, int N) {
  int i = blockIdx.x * 256 + threadIdx.x;
  if (i >= K * N) return;
  int k = i / N;
  int col = i - k * N;
  BfPair p = split2(W[i]);
  int t = k >> 5, rem = k & 31;
  int lg = rem >> 3, j = rem & 7;
  int cb = col >> 4, lr = col & 15;
  long o = ((long)(t * 16 + cb) * 64 + (lg * 16 + lr)) * 8 + j;
  Fh[o] = p.hi;
  Fl[o] = p.lo;
}

// A rows padded to 72 elems (144B); h rows padded to 264 (528B).
template <bool A3>
struct SMem {
  unsigned short ahi[2][64][72];           // A hi dbuf                 18 KB
  unsigned short alo[A3 ? 2 : 1][A3 ? 64 : 1][A3 ? 72 : 1];  // lo (3-prod only)
  unsigned short hh[64 * 264];             // h (bf16 hi)               33 KB
  float lnp[4][64][2];                     // LN partials                2 KB
};

// out = LN(silu(cat(segs)@W1+b1)@W2+b2)*g+b  [+residual store | atomic scatter]
// layer1: A3 ? 3-product : 2-product (A-hi RNE); layer2: 2-product.
// W1F/W2F are fragment-major packed (see wfrag_kernel).
template <int NSEG, bool SCATTER, bool A3>
__launch_bounds__(256, 2)
__global__ void mlp_mfma(
    const float* s0, const float* s1, const float* s2,
    const int* __restrict__ i1, const int* __restrict__ i2, int M,
    const unsigned short* __restrict__ W1Fh, const unsigned short* __restrict__ W1Fl,
    const float* __restrict__ b1,
    const unsigned short* __restrict__ W2Fh, const unsigned short* __restrict__ W2Fl,
    const float* __restrict__ b2,
    const float* __restrict__ gamma, const float* __restrict__ beta,
    const float* residual, float* outp,
    float* agg, const int* __restrict__ scat) {
  constexpr int K1 = NSEG * 256;
  constexpr int NT = K1 / 32;   // 32-k MFMA steps
  constexpr int NU = K1 / 64;   // 64-k macro steps (1 barrier each)
  __shared__ SMem<A3> sm;

  const int tid = threadIdx.x;
  const int w = tid >> 6;        // wave: owns output cols [w*64, w*64+64)
  const int l = tid & 63;
  const int lr = l & 15;
  const int lg = l >> 4;
  const int colbase = w * 64 + lr;
  const long blockRow = (long)blockIdx.x * 64;

  // staging: thread (w,l) stages row l, k-cols [w*16, w*16+16) of each macro tile
  const long grow_s = blockRow + l;
  const long growc = grow_s < M ? grow_s : (long)(M - 1);
  const float* rp0 = s0 + growc * Hdim;
  const float* rp1 = nullptr;
  const float* rp2 = nullptr;
  if (NSEG >= 2) rp1 = s1 + (long)(i1 ? i1[growc] : (int)growc) * Hdim;
  if (NSEG >= 3) rp2 = s2 + (long)(i2 ? i2[growc] : (int)growc) * Hdim;

  auto aptr = [&](int m) -> const float* {   // macro m covers k [m*64, m*64+64)
    const int seg = m >> 2;
    const float* rp = rp0;
    if (NSEG >= 2 && seg == 1) rp = rp1;
    if (NSEG >= 3 && seg == 2) rp = rp2;
    return rp + (m & 3) * 64 + w * 16;
  };

  auto loadA = [&](int m, float4* v) {
    const float* p = aptr(m);
#pragma unroll
    for (int i = 0; i < 4; ++i) v[i] = *(const float4*)(p + i * 4);
  };

  auto stageA = [&](int buf, const float4* v) {
    float in[16] = {v[0].x, v[0].y, v[0].z, v[0].w, v[1].x, v[1].y, v[1].z, v[1].w,
                    v[2].x, v[2].y, v[2].z, v[2].w, v[3].x, v[3].y, v[3].z, v[3].w};
    if constexpr (A3) {
      u16x8 th0, tl0, th1, tl1;
#pragma unroll
      for (int j = 0; j < 8; ++j) {
        BfPair p0 = split2t(in[j]);
        th0[j] = p0.hi; tl0[j] = p0.lo;
        BfPair p1 = split2t(in[j + 8]);
        th1[j] = p1.hi; tl1[j] = p1.lo;
      }
      *(u16x8*)&sm.ahi[buf][l][w * 16]     = th0;
      *(u16x8*)&sm.ahi[buf][l][w * 16 + 8] = th1;
      *(u16x8*)&sm.alo[buf][l][w * 16]     = tl0;
      *(u16x8*)&sm.alo[buf][l][w * 16 + 8] = tl1;
    } else {
      u16x8 th0, th1;
#pragma unroll
      for (int j = 0; j < 8; ++j) {
        th0[j] = f2bf(in[j]);       // RNE: unbiased without lo-compensation
        th1[j] = f2bf(in[j + 8]);
      }
      *(u16x8*)&sm.ahi[buf][l][w * 16]     = th0;
      *(u16x8*)&sm.ahi[buf][l][w * 16 + 8] = th1;
    }
  };

  // fragment-major B load: one contiguous 1KB burst per (t, colblk)
  auto loadB1 = [&](int t, bf16x8* bh, bf16x8* bl) {   // 32-k step t
#pragma unroll
    for (int n = 0; n < 4; ++n) {
      const long o = ((long)(t * 16 + w * 4 + n) * 64 + l) * 8;
      bh[n] = *(const bf16x8*)(W1Fh + o);
      bl[n] = *(const bf16x8*)(W1Fl + o);
    }
  };

  // ---------------- layer 1: cat(segs) @ W1 (macro-pipelined, A depth-2) ----------------
  f32x4 acc[4][4] = {};
  {
    float4 v[4];
    loadA(0, v);
    stageA(0, v);
  }
  float4 va[4], vb[4];               // A(u+1), A(u+2) in flight
  loadA(1 < NU ? 1 : NU - 1, va);
  bf16x8 bhc[4], blc[4];
  loadB1(0, bhc, blc);

  for (int u = 0; u < NU; ++u) {
    bar_lds();                       // buf[u&1] visible; no vmcnt drain
    // issue A(u+2) loads now
    loadA(u + 2 < NU ? u + 2 : NU - 1, vb);
    // ---- k-step s=0 (t = 2u) ----
    bf16x8 bhn[4], bln[4];
    loadB1(2 * u + 1 < NT ? 2 * u + 1 : NT - 1, bhn, bln);
    bf16x8 ah[4], al[4];
#pragma unroll
    for (int rb = 0; rb < 4; ++rb) {
      ah[rb] = *(const bf16x8*)&sm.ahi[u & 1][rb * 16 + lr][lg * 8];
      if constexpr (A3) al[rb] = *(const bf16x8*)&sm.alo[u & 1][rb * 16 + lr][lg * 8];
    }
    __builtin_amdgcn_s_setprio(1);
#pragma unroll
    for (int rb = 0; rb < 4; ++rb)
#pragma unroll
      for (int n = 0; n < 4; ++n) {
        acc[rb][n] = __builtin_amdgcn_mfma_f32_16x16x32_bf16(ah[rb], bhc[n], acc[rb][n], 0, 0, 0);
        acc[rb][n] = __builtin_amdgcn_mfma_f32_16x16x32_bf16(ah[rb], blc[n], acc[rb][n], 0, 0, 0);
        if constexpr (A3)
          acc[rb][n] = __builtin_amdgcn_mfma_f32_16x16x32_bf16(al[rb], bhc[n], acc[rb][n], 0, 0, 0);
      }
    __builtin_amdgcn_s_setprio(0);
    // ---- k-step s=1 (t = 2u+1) ----
    bf16x8 bh2[4], bl2[4];
    loadB1(2 * u + 2 < NT ? 2 * u + 2 : NT - 1, bh2, bl2);
#pragma unroll
    for (int rb = 0; rb < 4; ++rb) {
      ah[rb] = *(const bf16x8*)&sm.ahi[u & 1][rb * 16 + lr][32 + lg * 8];
      if constexpr (A3) al[rb] = *(const bf16x8*)&sm.alo[u & 1][rb * 16 + lr][32 + lg * 8];
    }
    __builtin_amdgcn_s_setprio(1);
#pragma unroll
    for (int rb = 0; rb < 4; ++rb)
#pragma unroll
      for (int n = 0; n < 4; ++n) {
        acc[rb][n] = __builtin_amdgcn_mfma_f32_16x16x32_bf16(ah[rb], bhn[n], acc[rb][n], 0, 0, 0);
        acc[rb][n] = __builtin_amdgcn_mfma_f32_16x16x32_bf16(ah[rb], bln[n], acc[rb][n], 0, 0, 0);
        if constexpr (A3)
          acc[rb][n] = __builtin_amdgcn_mfma_f32_16x16x32_bf16(al[rb], bhn[n], acc[rb][n], 0, 0, 0);
      }
    __builtin_amdgcn_s_setprio(0);
    // ---- stage A(u+1) ----
    if (u + 1 < NU) stageA((u + 1) & 1, va);
#pragma unroll
    for (int i = 0; i < 4; ++i) va[i] = vb[i];
#pragma unroll
    for (int n = 0; n < 4; ++n) { bhc[n] = bh2[n]; blc[n] = bl2[n]; }
  }

  // issue B2(0) prefetch early (hides under SiLU + h-store)
  bf16x8 b2hc[4], b2lc[4];
#pragma unroll
  for (int n = 0; n < 4; ++n) {
    const long o = ((long)(w * 4 + n) * 64 + l) * 8;
    b2hc[n] = *(const bf16x8*)(W2Fh + o);
    b2lc[n] = *(const bf16x8*)(W2Fl + o);
  }

  // ---------------- bias1 + SiLU -> h (bf16 hi, padded rows) ----------------
  float bb1[4];
#pragma unroll
  for (int n = 0; n < 4; ++n) bb1[n] = b1[colbase + n * 16];
#pragma unroll
  for (int rb = 0; rb < 4; ++rb) {
#pragma unroll
    for (int n = 0; n < 4; ++n) {
      const int col = colbase + n * 16;
#pragma unroll
      for (int r = 0; r < 4; ++r) {
        const int row = rb * 16 + lg * 4 + r;
        float v = acc[rb][n][r] + bb1[n];
        v = v / (1.0f + __expf(-v));
        sm.hh[row * 264 + col] = f2bf(v);
      }
    }
  }
  bar_lds();

  // ---------------- layer 2: h @ W2 (2-product, no barriers) ----------------
  f32x4 acc2[4][4] = {};
  for (int ks = 0; ks < 8; ++ks) {
    const int kn = (ks + 1 < 8) ? ks + 1 : ks;
    bf16x8 b2hn[4], b2ln[4];
#pragma unroll
    for (int n = 0; n < 4; ++n) {
      const long o = ((long)(kn * 16 + w * 4 + n) * 64 + l) * 8;
      b2hn[n] = *(const bf16x8*)(W2Fh + o);
      b2ln[n] = *(const bf16x8*)(W2Fl + o);
    }
    bf16x8 ah[4];
#pragma unroll
    for (int rb = 0; rb < 4; ++rb) {
      const int row = rb * 16 + lr;
      ah[rb] = *(const bf16x8*)&sm.hh[row * 264 + ks * 32 + lg * 8];
    }
    __builtin_amdgcn_s_setprio(1);
#pragma unroll
    for (int rb = 0; rb < 4; ++rb)
#pragma unroll
      for (int n = 0; n < 4; ++n) {
        acc2[rb][n] = __builtin_amdgcn_mfma_f32_16x16x32_bf16(ah[rb], b2hc[n], acc2[rb][n], 0, 0, 0);
        acc2[rb][n] = __builtin_amdgcn_mfma_f32_16x16x32_bf16(ah[rb], b2lc[n], acc2[rb][n], 0, 0, 0);
      }
    __builtin_amdgcn_s_setprio(0);
#pragma unroll
    for (int n = 0; n < 4; ++n) { b2hc[n] = b2hn[n]; b2lc[n] = b2ln[n]; }
  }

  // ---------------- LayerNorm in registers (two-pass) + epilogue ----------------
  float bb2[4], gmv[4], btv[4];
#pragma unroll
  for (int n = 0; n < 4; ++n) {
    const int c = colbase + n * 16;
    bb2[n] = b2[c];
    gmv[n] = gamma[c];
    btv[n] = beta[c];
  }
  float psum[16];
#pragma unroll
  for (int rb = 0; rb < 4; ++rb)
#pragma unroll
    for (int r = 0; r < 4; ++r) {
      float s = 0.f;
#pragma unroll
      for (int n = 0; n < 4; ++n) s += acc2[rb][n][r] + bb2[n];
      psum[rb * 4 + r] = s;
    }
#pragma unroll
  for (int i = 0; i < 16; ++i) {
    psum[i] += __shfl_xor(psum[i], 1, 64);
    psum[i] += __shfl_xor(psum[i], 2, 64);
    psum[i] += __shfl_xor(psum[i], 4, 64);
    psum[i] += __shfl_xor(psum[i], 8, 64);
  }
  if (lr == 0) {
#pragma unroll
    for (int rb = 0; rb < 4; ++rb)
#pragma unroll
      for (int r = 0; r < 4; ++r)
        sm.lnp[w][rb * 16 + lg * 4 + r][0] = psum[rb * 4 + r];
  }
  __syncthreads();
  float mu[16];
#pragma unroll
  for (int rb = 0; rb < 4; ++rb)
#pragma unroll
    for (int r = 0; r < 4; ++r) {
      const int row = rb * 16 + lg * 4 + r;
      mu[rb * 4 + r] = (sm.lnp[0][row][0] + sm.lnp[1][row][0] +
                        sm.lnp[2][row][0] + sm.lnp[3][row][0]) * (1.0f / 256.0f);
    }
  float psq[16];
#pragma unroll
  for (int rb = 0; rb < 4; ++rb)
#pragma unroll
    for (int r = 0; r < 4; ++r) {
      float s = 0.f;
#pragma unroll
      for (int n = 0; n < 4; ++n) {
        const float d = acc2[rb][n][r] + bb2[n] - mu[rb * 4 + r];
        s += d * d;
      }
      psq[rb * 4 + r] = s;
    }
#pragma unroll
  for (int i = 0; i < 16; ++i) {
    psq[i] += __shfl_xor(psq[i], 1, 64);
    psq[i] += __shfl_xor(psq[i], 2, 64);
    psq[i] += __shfl_xor(psq[i], 4, 64);
    psq[i] += __shfl_xor(psq[i], 8, 64);
  }
  if (lr == 0) {
#pragma unroll
    for (int rb = 0; rb < 4; ++rb)
#pragma unroll
      for (int r = 0; r < 4; ++r)
        sm.lnp[w][rb * 16 + lg * 4 + r][1] = psq[rb * 4 + r];
  }
  __syncthreads();
#pragma unroll
  for (int rb = 0; rb < 4; ++rb) {
#pragma unroll
    for (int r = 0; r < 4; ++r) {
      const int row = rb * 16 + lg * 4 + r;
      const long grow = blockRow + row;
      if (grow >= M) continue;
      const float var = (sm.lnp[0][row][1] + sm.lnp[1][row][1] +
                         sm.lnp[2][row][1] + sm.lnp[3][row][1]) * (1.0f / 256.0f);
      const float rstd = 1.0f / sqrtf(var + 1e-5f);
      const float m = mu[rb * 4 + r];
      if constexpr (SCATTER) {
        const int d = scat[grow];
        float* ap = agg + (long)d * Hdim;
#pragma unroll
        for (int n = 0; n < 4; ++n) {
          const int c = colbase + n * 16;
          atomicAdd(ap + c, (acc2[rb][n][r] + bb2[n] - m) * rstd * gmv[n] + btv[n]);
        }
      } else {
        const long o = grow * Hdim;
#pragma unroll
        for (int n = 0; n < 4; ++n) {
          const int c = colbase + n * 16;
          outp[o + c] = (acc2[rb][n][r] + bb2[n] - m) * rstd * gmv[n] + btv[n] + residual[o + c];
        }
      }
    }
  }
}

extern "C" void kernel_launch(void* const* d_in, const int* in_sizes, int n_in,
                              void* d_out, int out_size, void* d_ws, size_t ws_size,
                              hipStream_t stream) {
  const float* g2m   = (const float*)d_in[0];
  const float* gridf = (const float*)d_in[1];
  const float* meshf = (const float*)d_in[2];
  const int*   src   = (const int*)d_in[3];
  const int*   dst   = (const int*)d_in[4];
  const float* eW1 = (const float*)d_in[5];  const float* eb1 = (const float*)d_in[6];
  const float* eW2 = (const float*)d_in[7];  const float* eb2 = (const float*)d_in[8];
  const float* eg  = (const float*)d_in[9];  const float* ebt = (const float*)d_in[10];
  const float* sW1 = (const float*)d_in[11]; const float* sb1 = (const float*)d_in[12];
  const float* sW2 = (const float*)d_in[13]; const float* sb2 = (const float*)d_in[14];
  const float* sg  = (const float*)d_in[15]; const float* sbt = (const float*)d_in[16];
  const float* dW1 = (const float*)d_in[17]; const float* db1 = (const float*)d_in[18];
  const float* dW2 = (const float*)d_in[19]; const float* db2 = (const float*)d_in[20];
  const float* dg  = (const float*)d_in[21]; const float* dbt = (const float*)d_in[22];

  float* out_grid = (float*)d_out;
  float* out_mesh = out_grid + (long)NG_N * Hdim;  // doubles as agg accumulator

  // fragment-major split-bf16 weights in workspace (~2.4 MB)
  unsigned short* p = (unsigned short*)d_ws;
  unsigned short* eW1Fh = p; p += 768 * 256;  unsigned short* eW1Fl = p; p += 768 * 256;
  unsigned short* eW2Fh = p; p += 256 * 256;  unsigned short* eW2Fl = p; p += 256 * 256;
  unsigned short* sW1Fh = p; p += 256 * 256;  unsigned short* sW1Fl = p; p += 256 * 256;
  unsigned short* sW2Fh = p; p += 256 * 256;  unsigned short* sW2Fl = p; p += 256 * 256;
  unsigned short* dW1Fh = p; p += 512 * 256;  unsigned short* dW1Fl = p; p += 512 * 256;
  unsigned short* dW2Fh = p; p += 256 * 256;  unsigned short* dW2Fl = p; p += 256 * 256;

  auto WF = [&](const float* W, unsigned short* Fh, unsigned short* Fl, int K, int N) {
    int tot = K * N;
    wfrag_kernel<<<(tot + 255) / 256, 256, 0, stream>>>(W, Fh, Fl, K, N);
  };
  WF(eW1, eW1Fh, eW1Fl, 768, 256);
  WF(eW2, eW2Fh, eW2Fl, 256, 256);
  WF(sW1, sW1Fh, sW1Fl, 256, 256);
  WF(sW2, sW2Fh, sW2Fl, 256, 256);
  WF(dW1, dW1Fh, dW1Fl, 512, 256);
  WF(dW2, dW2Fh, dW2Fl, 256, 256);

  // zero the agg accumulator (mesh output region)
  (void)hipMemsetAsync(out_mesh, 0, (size_t)NM_N * Hdim * sizeof(float), stream);

  // edge MLP (2-product layer1): cat[g2m, grid[src], mesh[dst]] -> scatter into agg
  mlp_mfma<3, true, false><<<(E_N + 63) / 64, 256, 0, stream>>>(
      g2m, gridf, meshf, src, dst, E_N,
      eW1Fh, eW1Fl, eb1, eW2Fh, eW2Fl, eb2, eg, ebt,
      nullptr, nullptr, out_mesh, dst);

  // grid MLP (3-product): grid_new = grid + MLP(grid)
  mlp_mfma<1, false, true><<<(NG_N + 63) / 64, 256, 0, stream>>>(
      gridf, nullptr, nullptr, nullptr, nullptr, NG_N,
      sW1Fh, sW1Fl, sb1, sW2Fh, sW2Fl, sb2, sg, sbt,
      gridf, out_grid, nullptr, nullptr);

  // mesh MLP (3-product): mesh_new = mesh + MLP(cat[agg, mesh])
  mlp_mfma<2, false, true><<<(NM_N + 63) / 64, 256, 0, stream>>>(
      out_mesh, meshf, nullptr, nullptr, nullptr, NM_N,
      dW1Fh, dW1Fl, db1, dW2Fh, dW2Fl, db2, dg, dbt,
      meshf, out_mesh, nullptr, nullptr);
}